// Round 1
// baseline (284.640 us; speedup 1.0000x reference)
//
#include <hip/hip_runtime.h>
#include <math.h>

// Problem constants (fixed by setup_inputs)
#define NB   16      // batch
#define NC   64      // channels
#define HWs  4096    // H*W
#define NPS  1024    // pooled spatial (32*32)
#define TQ   128     // queries per block
#define TS   64      // key tile size
#define SSTR 68      // LDS p-row stride in floats (mult of 4 for b128 alignment)

// ws layout (floats)
static constexpr size_t THETA_OFF = 0;                                // [NB][HWs][8]
static constexpr size_t PHI_OFF   = (size_t)NB * HWs * 8;             // [NB][NPS][8]
static constexpr size_t G_OFF     = PHI_OFF + (size_t)NB * NPS * 8;   // [NB][NPS][32]
// total = 1,179,648 floats = 4.5 MB

// ---------------------------------------------------------------------------
// Kernel 1: projections.
// blocks 0..255  : theta = Wt @ x            -> theta[b][q][0..7]
// blocks 256..319: phi = maxpool2(Wp @ x)    -> phi[b][ps][0..7]
//                  g   = maxpool2(Wg @ x)    -> g[b][ps][0..31]
// ---------------------------------------------------------------------------
__global__ __launch_bounds__(256) void k_proj(
    const float* __restrict__ x, const float* __restrict__ Wt,
    const float* __restrict__ Wp, const float* __restrict__ Wg,
    float* __restrict__ ws)
{
    float* theta = ws + THETA_OFF;
    float* phi   = ws + PHI_OFF;
    float* g     = ws + G_OFF;
    const int blk = blockIdx.x;
    const int tid = threadIdx.x;

    if (blk < 256) {
        // ---- theta: one thread per (b, q) ----
        const int b  = blk >> 4;
        const int q  = ((blk & 15) << 8) + tid;
        float acc[8];
#pragma unroll
        for (int j = 0; j < 8; ++j) acc[j] = 0.f;
        const float* xb = x + (size_t)b * NC * HWs + q;
        for (int ci = 0; ci < NC; ++ci) {
            float xv = xb[(size_t)ci * HWs];           // coalesced across lanes
#pragma unroll
            for (int j = 0; j < 8; ++j) acc[j] += Wt[j * NC + ci] * xv;  // scalar loads
        }
        float* dst = theta + ((size_t)b * HWs + q) * 8;
        *(float4*)(dst)     = make_float4(acc[0], acc[1], acc[2], acc[3]);
        *(float4*)(dst + 4) = make_float4(acc[4], acc[5], acc[6], acc[7]);
    } else {
        // ---- pooled phi/g: one thread per (b, ps) ----
        const int idx = blk - 256;                     // 0..63
        const int b   = idx >> 2;
        const int ps  = ((idx & 3) << 8) + tid;        // 0..1023
        const int py  = ps >> 5, px = ps & 31;
        float mp[8], mg[32];
#pragma unroll
        for (int j = 0; j < 8; ++j)  mp[j] = -1e30f;
#pragma unroll
        for (int j = 0; j < 32; ++j) mg[j] = -1e30f;
        const float* xb = x + (size_t)b * NC * HWs;
#pragma unroll
        for (int dy = 0; dy < 2; ++dy) {
#pragma unroll
            for (int dx = 0; dx < 2; ++dx) {
                const int pix = (2 * py + dy) * 64 + 2 * px + dx;
                float cp[8], cg[32];
#pragma unroll
                for (int j = 0; j < 8; ++j)  cp[j] = 0.f;
#pragma unroll
                for (int j = 0; j < 32; ++j) cg[j] = 0.f;
                for (int ci = 0; ci < NC; ++ci) {
                    float xv = xb[(size_t)ci * HWs + pix];
#pragma unroll
                    for (int j = 0; j < 8; ++j)  cp[j] += Wp[j * NC + ci] * xv;
#pragma unroll
                    for (int j = 0; j < 32; ++j) cg[j] += Wg[j * NC + ci] * xv;
                }
#pragma unroll
                for (int j = 0; j < 8; ++j)  mp[j] = fmaxf(mp[j], cp[j]);
#pragma unroll
                for (int j = 0; j < 32; ++j) mg[j] = fmaxf(mg[j], cg[j]);
            }
        }
        float* pd = phi + ((size_t)b * NPS + ps) * 8;
        *(float4*)(pd)     = make_float4(mp[0], mp[1], mp[2], mp[3]);
        *(float4*)(pd + 4) = make_float4(mp[4], mp[5], mp[6], mp[7]);
        float* gd = g + ((size_t)b * NPS + ps) * 32;
#pragma unroll
        for (int k = 0; k < 8; ++k)
            *(float4*)(gd + 4 * k) = make_float4(mg[4*k], mg[4*k+1], mg[4*k+2], mg[4*k+3]);
    }
}

// ---------------------------------------------------------------------------
// Kernel 2: fused flash-style attention + output conv + residual.
// One block = one batch x 128-query tile. Online softmax over 16 key tiles.
// Thread (qg = tid>>2, cg = tid&3) owns queries {qg, qg+64} x channels
// [cg*8, cg*8+8).
// ---------------------------------------------------------------------------
__global__ __launch_bounds__(256) void k_attn(
    const float* __restrict__ x, const float* __restrict__ Wo,
    const float* __restrict__ gamma_p, const float* __restrict__ ws,
    float* __restrict__ out)
{
    __shared__ float P[TQ][SSTR];        // softmax p values (reused as o-tile in epilogue)
    __shared__ float pmax_s[TQ][4];
    __shared__ float psum_s[TQ][4];
    __shared__ float phi_t[TS][8];
    __shared__ float g_t[TS][32];

    const float* theta = ws + THETA_OFF;
    const float* phi   = ws + PHI_OFF;
    const float* g     = ws + G_OFF;

    const int tid = threadIdx.x;
    const int blk = blockIdx.x;
    const int b   = blk >> 5;                 // 16 batches
    const int q0  = (blk & 31) * TQ;          // query-tile origin
    const int qg  = tid >> 2;                 // 0..63
    const int cg  = tid & 3;                  // 0..3
    const int c0  = cg * 8;

    // theta fragments for the two owned queries (read once, L2-cached)
    float th0[8], th1[8];
    {
        const float* t0 = theta + ((size_t)b * HWs + q0 + qg) * 8;
        const float* t1 = theta + ((size_t)b * HWs + q0 + qg + 64) * 8;
#pragma unroll
        for (int j = 0; j < 8; ++j) { th0[j] = t0[j]; th1[j] = t1[j]; }
    }

    float o0[8], o1[8];
#pragma unroll
    for (int j = 0; j < 8; ++j) { o0[j] = 0.f; o1[j] = 0.f; }
    float m0 = -1e30f, m1 = -1e30f;
    float l0 = 0.f,    l1 = 0.f;

    for (int t = 0; t < 16; ++t) {
        const int s0 = t * TS;
        __syncthreads();                       // protect LDS from previous iter readers

        // ---- stage phi tile (512 floats) and g tile (2048 floats) ----
        if (tid < 128) {
            float4 v = *(const float4*)(phi + ((size_t)b * NPS + s0) * 8 + tid * 4);
            *(float4*)(&phi_t[0][0] + tid * 4) = v;
        }
        {
            const float* src = g + ((size_t)b * NPS + s0) * 32 + tid * 8;
            float4 v0 = *(const float4*)(src);
            float4 v1 = *(const float4*)(src + 4);
            *(float4*)(&g_t[0][0] + tid * 8)     = v0;
            *(float4*)(&g_t[0][0] + tid * 8 + 4) = v1;
        }
        __syncthreads();

        // ---- scores for 2 queries x 16 keys (keys s = cg*16 + j) ----
        float sc0[16], sc1[16];
#pragma unroll
        for (int j = 0; j < 16; ++j) {
            const int sl = cg * 16 + j;
            float4 pa = *(const float4*)&phi_t[sl][0];
            float4 pb = *(const float4*)&phi_t[sl][4];
            sc0[j] = th0[0]*pa.x + th0[1]*pa.y + th0[2]*pa.z + th0[3]*pa.w
                   + th0[4]*pb.x + th0[5]*pb.y + th0[6]*pb.z + th0[7]*pb.w;
            sc1[j] = th1[0]*pa.x + th1[1]*pa.y + th1[2]*pa.z + th1[3]*pa.w
                   + th1[4]*pb.x + th1[5]*pb.y + th1[6]*pb.z + th1[7]*pb.w;
        }

        // ---- cross-thread max ----
        float a0 = sc0[0], a1 = sc1[0];
#pragma unroll
        for (int j = 1; j < 16; ++j) { a0 = fmaxf(a0, sc0[j]); a1 = fmaxf(a1, sc1[j]); }
        pmax_s[qg][cg]      = a0;
        pmax_s[qg + 64][cg] = a1;
        __syncthreads();
        float4 r0 = *(const float4*)&pmax_s[qg][0];
        float4 r1 = *(const float4*)&pmax_s[qg + 64][0];
        const float mn0 = fmaxf(m0, fmaxf(fmaxf(r0.x, r0.y), fmaxf(r0.z, r0.w)));
        const float mn1 = fmaxf(m1, fmaxf(fmaxf(r1.x, r1.y), fmaxf(r1.z, r1.w)));
        const float al0 = __expf(m0 - mn0);
        const float al1 = __expf(m1 - mn1);

        // ---- p = exp(sc - m), write to LDS, partial sums ----
        float s_own0 = 0.f, s_own1 = 0.f;
#pragma unroll
        for (int j = 0; j < 16; ++j) {
            sc0[j] = __expf(sc0[j] - mn0); s_own0 += sc0[j];
            sc1[j] = __expf(sc1[j] - mn1); s_own1 += sc1[j];
        }
#pragma unroll
        for (int k = 0; k < 4; ++k) {
            *(float4*)&P[qg][cg * 16 + 4 * k] =
                make_float4(sc0[4*k], sc0[4*k+1], sc0[4*k+2], sc0[4*k+3]);
            *(float4*)&P[qg + 64][cg * 16 + 4 * k] =
                make_float4(sc1[4*k], sc1[4*k+1], sc1[4*k+2], sc1[4*k+3]);
        }
        psum_s[qg][cg]      = s_own0;
        psum_s[qg + 64][cg] = s_own1;
        __syncthreads();
        float4 u0 = *(const float4*)&psum_s[qg][0];
        float4 u1 = *(const float4*)&psum_s[qg + 64][0];
        l0 = l0 * al0 + (u0.x + u0.y + u0.z + u0.w);
        l1 = l1 * al1 + (u1.x + u1.y + u1.z + u1.w);
        m0 = mn0; m1 = mn1;
#pragma unroll
        for (int j = 0; j < 8; ++j) { o0[j] *= al0; o1[j] *= al1; }

        // ---- o update: o[c] += sum_s p[q][s] * g[s][c] ----
#pragma unroll 16
        for (int s = 0; s < TS; ++s) {
            const float p0 = P[qg][s];
            const float p1 = P[qg + 64][s];
            float4 ga = *(const float4*)&g_t[s][c0];
            float4 gb = *(const float4*)&g_t[s][c0 + 4];
            o0[0] += p0 * ga.x; o0[1] += p0 * ga.y; o0[2] += p0 * ga.z; o0[3] += p0 * ga.w;
            o0[4] += p0 * gb.x; o0[5] += p0 * gb.y; o0[6] += p0 * gb.z; o0[7] += p0 * gb.w;
            o1[0] += p1 * ga.x; o1[1] += p1 * ga.y; o1[2] += p1 * ga.z; o1[3] += p1 * ga.w;
            o1[4] += p1 * gb.x; o1[5] += p1 * gb.y; o1[6] += p1 * gb.z; o1[7] += p1 * gb.w;
        }
    }

    // ---- epilogue: normalize, round-trip o through LDS, apply Wo, residual ----
    __syncthreads();                           // last o-phase reads of P done
    float* otile = &P[0][0];                   // reuse as [32][TQ]
    const float inv0 = 1.f / l0, inv1 = 1.f / l1;
#pragma unroll
    for (int j = 0; j < 8; ++j) {
        otile[(c0 + j) * TQ + qg]      = o0[j] * inv0;
        otile[(c0 + j) * TQ + qg + 64] = o1[j] * inv1;
    }
    __syncthreads();

    const int qe   = tid & 127;                // 0..127
    const int half = tid >> 7;                 // 0/1, wave-uniform
    float acc[32];
#pragma unroll
    for (int j = 0; j < 32; ++j) acc[j] = 0.f;
    for (int c = 0; c < 32; ++c) {
        const float ov = otile[c * TQ + qe];
#pragma unroll
        for (int j = 0; j < 32; ++j)
            acc[j] += Wo[(half * 32 + j) * 32 + c] * ov;   // wave-uniform -> s_loads
    }
    const float gam = gamma_p[0];
#pragma unroll
    for (int j = 0; j < 32; ++j) {
        const size_t a = ((size_t)(b * NC + half * 32 + j)) * HWs + q0 + qe;
        out[a] = gam * acc[j] + x[a];          // coalesced
    }
}

extern "C" void kernel_launch(void* const* d_in, const int* in_sizes, int n_in,
                              void* d_out, int out_size, void* d_ws, size_t ws_size,
                              hipStream_t stream) {
    const float* x     = (const float*)d_in[0];
    const float* Wt    = (const float*)d_in[1];
    const float* Wp    = (const float*)d_in[2];
    const float* Wg    = (const float*)d_in[3];
    const float* Wo    = (const float*)d_in[4];
    const float* gamma = (const float*)d_in[5];
    float* out = (float*)d_out;
    float* ws  = (float*)d_ws;

    k_proj<<<320, 256, 0, stream>>>(x, Wt, Wp, Wg, ws);
    k_attn<<<512, 256, 0, stream>>>(x, Wo, gamma, ws, out);
}

// Round 3
// 164.256 us; speedup vs baseline: 1.7329x; 1.7329x over previous
//
#include <hip/hip_runtime.h>
#include <math.h>

// Problem constants
#define NB   16
#define NC   64
#define HWs  4096
#define NPS  1024
#define LOG2E 1.44269504088896341f

// ws layout in ushort (bf16 bit patterns)
static constexpr size_t PHI_OFF = (size_t)NB * HWs * 8;            // theta: [b][4096][8]
static constexpr size_t GT_OFF  = PHI_OFF + (size_t)NB * NPS * 8;  // phi:   [b][1024][8]
// gT: [b][32][1024]; total 1,179,648 ushorts = 2.25 MB

typedef short s16x8 __attribute__((ext_vector_type(8)));
typedef float f32x4 __attribute__((ext_vector_type(4)));

#define LD8G(p) (*(const s16x8*)(p))

__device__ inline unsigned short f2bf(float f) {
    unsigned int u = __float_as_uint(f);
    u += 0x7fffu + ((u >> 16) & 1u);          // RNE
    return (unsigned short)(u >> 16);
}
__device__ inline unsigned int pk2(float a, float b) {
    unsigned int ua = __float_as_uint(a); ua += 0x7fffu + ((ua >> 16) & 1u);
    unsigned int ub = __float_as_uint(b); ub += 0x7fffu + ((ub >> 16) & 1u);
    return (ua >> 16) | (ub & 0xffff0000u);
}

// ---------------------------------------------------------------------------
// Kernel 1: projections -> bf16.  (unchanged from round 2; audited correct)
// blocks 0..255  : theta = (Wt @ x) * log2e          -> theta[b][q][8] bf16
// blocks 256..383: phi = maxpool2(Wp @ x)            -> phi[b][ps][8] bf16
//                  gT  = maxpool2(Wg @ x) transposed -> gT[b][c][ps]  bf16
// ---------------------------------------------------------------------------
__global__ __launch_bounds__(256) void k_proj(
    const float* __restrict__ x, const float* __restrict__ Wt,
    const float* __restrict__ Wp, const float* __restrict__ Wg,
    unsigned short* __restrict__ ws)
{
    unsigned short* theta = ws;
    unsigned short* phi   = ws + PHI_OFF;
    unsigned short* gT    = ws + GT_OFF;
    const int blk = blockIdx.x;
    const int tid = threadIdx.x;

    if (blk < 256) {
        const int b = blk >> 4;
        const int q = ((blk & 15) << 8) + tid;
        float acc[8];
#pragma unroll
        for (int j = 0; j < 8; ++j) acc[j] = 0.f;
        const float* xb = x + (size_t)b * NC * HWs + q;
        for (int ci = 0; ci < NC; ++ci) {
            float xv = xb[(size_t)ci * HWs];
#pragma unroll
            for (int j = 0; j < 8; ++j) acc[j] += Wt[j * NC + ci] * xv;
        }
        uint4 pkd;
        pkd.x = pk2(acc[0] * LOG2E, acc[1] * LOG2E);
        pkd.y = pk2(acc[2] * LOG2E, acc[3] * LOG2E);
        pkd.z = pk2(acc[4] * LOG2E, acc[5] * LOG2E);
        pkd.w = pk2(acc[6] * LOG2E, acc[7] * LOG2E);
        *(uint4*)(theta + ((size_t)b * HWs + q) * 8) = pkd;
    } else {
        const int idx = blk - 256;            // 0..127
        const int b   = idx >> 3;
        const int pyg = idx & 7;
        const int col = tid & 63;             // = 2*px + dx
        const int pyi = tid >> 6;             // 0..3
        const int py  = pyg * 4 + pyi;
        const int dx  = col & 1;
        const int px  = col >> 1;
        const int r0  = 2 * py;

        float cp0[8], cp1[8], cg0[32], cg1[32];
#pragma unroll
        for (int j = 0; j < 8; ++j)  { cp0[j] = 0.f; cp1[j] = 0.f; }
#pragma unroll
        for (int j = 0; j < 32; ++j) { cg0[j] = 0.f; cg1[j] = 0.f; }
        const float* xb = x + (size_t)b * NC * HWs + r0 * 64 + col;
        for (int ci = 0; ci < NC; ++ci) {
            const float xv0 = xb[(size_t)ci * HWs];
            const float xv1 = xb[(size_t)ci * HWs + 64];
#pragma unroll
            for (int j = 0; j < 8; ++j) {
                cp0[j] += Wp[j * NC + ci] * xv0;
                cp1[j] += Wp[j * NC + ci] * xv1;
            }
#pragma unroll
            for (int j = 0; j < 32; ++j) {
                cg0[j] += Wg[j * NC + ci] * xv0;
                cg1[j] += Wg[j * NC + ci] * xv1;
            }
        }
        float p[8], g[32];
#pragma unroll
        for (int j = 0; j < 8; ++j)  p[j] = fmaxf(cp0[j], cp1[j]);
#pragma unroll
        for (int j = 0; j < 32; ++j) g[j] = fmaxf(cg0[j], cg1[j]);
#pragma unroll
        for (int j = 0; j < 8; ++j)  p[j] = fmaxf(p[j], __shfl_xor(p[j], 1));
#pragma unroll
        for (int j = 0; j < 32; ++j) g[j] = fmaxf(g[j], __shfl_xor(g[j], 1));

        const int ps = py * 32 + px;
        if (dx == 0) {
            uint4 pkd;
            pkd.x = pk2(p[0], p[1]); pkd.y = pk2(p[2], p[3]);
            pkd.z = pk2(p[4], p[5]); pkd.w = pk2(p[6], p[7]);
            *(uint4*)(phi + ((size_t)b * NPS + ps) * 8) = pkd;
        }
#pragma unroll
        for (int j = 0; j < 16; ++j) {
            const int c = dx * 16 + j;
            gT[((size_t)b * 32 + c) * NPS + ps] = f2bf(g[c]);
        }
    }
}

// ---------------------------------------------------------------------------
// Kernel 2: MFMA flash attention + Wo + residual (m120 orientation).
// Wave owns 32 queries; per 64-key tile:
//   S = mfma(A=theta rows=q, B=phi cols=s) x8   -> D rows q=quad*4+r, cols s=lr
//   softmax state (m,l,alpha) per-lane f32x4, indexed EXACTLY like O regs;
//   s-reduction = butterfly shfl_xor {1,2,4,8} (within 16-lane group)
//   P -> bf16 scalar stores, LDS [32 q][72 s]  (verified D->A round trip)
//   O += mfma(A=P from LDS, B=gT from global) x8 -> D rows q=quad*4+r (match!)
// No cross-wave sync in main loop; no LDS broadcast of softmax state.
// ---------------------------------------------------------------------------
__global__ __launch_bounds__(256) void k_attn(
    const float* __restrict__ x, const float* __restrict__ Wo,
    const float* __restrict__ gamma_p, const unsigned short* __restrict__ ws,
    float* __restrict__ out)
{
    __shared__ __align__(16) unsigned char smem[18432];  // P: 4 waves x 32 x 72 x 2B; epilogue: otile[32][132] f32

    const int tid  = threadIdx.x;
    const int wave = tid >> 6, lane = tid & 63;
    const int quad = lane >> 4, lr = lane & 15;
    const int blk  = blockIdx.x;
    const int b    = blk >> 5;
    const int q0   = (blk & 31) * 128;
    const int qw0  = q0 + wave * 32;

    const unsigned short* th = ws + (size_t)b * HWs * 8;
    const unsigned short* ph = ws + PHI_OFF + (size_t)b * NPS * 8;
    const unsigned short* gp = ws + GT_OFF + (size_t)b * 32 * NPS;
    unsigned short* Pw = (unsigned short*)smem + wave * 2304;   // [32 q][72 s] bf16

    const s16x8 zf = {0, 0, 0, 0, 0, 0, 0, 0};

    // theta A-fragments: A[m=q=lr][k=quad*8+j], real k<8 in quad 0
    s16x8 thA[2];
#pragma unroll
    for (int qs = 0; qs < 2; ++qs)
        thA[qs] = (quad == 0) ? LD8G(th + (size_t)(qw0 + qs * 16 + lr) * 8) : zf;

    f32x4 O[2][2];
    f32x4 m_[2], l_[2];
#pragma unroll
    for (int qs = 0; qs < 2; ++qs) {
#pragma unroll
        for (int r = 0; r < 4; ++r) { m_[qs][r] = -1e30f; l_[qs][r] = 0.f; }
#pragma unroll
        for (int cs = 0; cs < 2; ++cs)
#pragma unroll
            for (int r = 0; r < 4; ++r) O[qs][cs][r] = 0.f;
    }

    for (int t = 0; t < 16; ++t) {
        const int s0 = t * 64;

        // phi B-fragments: B[n=s=lr][k=quad*8+j], real k<8 in quad 0
        s16x8 phB[4];
#pragma unroll
        for (int ss = 0; ss < 4; ++ss)
            phB[ss] = (quad == 0) ? LD8G(ph + (size_t)(s0 + ss * 16 + lr) * 8) : zf;

        // scores: D[q][s]; lane reg r holds S[q = qs*16+quad*4+r][s = ss*16+lr]
        f32x4 S[2][4];
        const f32x4 zc = {0.f, 0.f, 0.f, 0.f};
#pragma unroll
        for (int qs = 0; qs < 2; ++qs)
#pragma unroll
            for (int ss = 0; ss < 4; ++ss)
                S[qs][ss] = __builtin_amdgcn_mfma_f32_16x16x32_bf16(thA[qs], phB[ss], zc, 0, 0, 0);

#pragma unroll
        for (int qs = 0; qs < 2; ++qs) {
            // per-q max over this tile's 64 s: lane-local over ss, butterfly over lr
            f32x4 tm = S[qs][0];
#pragma unroll
            for (int ss = 1; ss < 4; ++ss)
#pragma unroll
                for (int r = 0; r < 4; ++r) tm[r] = fmaxf(tm[r], S[qs][ss][r]);
#pragma unroll
            for (int r = 0; r < 4; ++r) {
                float v = tm[r];
                v = fmaxf(v, __shfl_xor(v, 1));
                v = fmaxf(v, __shfl_xor(v, 2));
                v = fmaxf(v, __shfl_xor(v, 4));
                v = fmaxf(v, __shfl_xor(v, 8));
                tm[r] = v;
            }
            f32x4 mn, al, ps_;
#pragma unroll
            for (int r = 0; r < 4; ++r) {
                mn[r] = fmaxf(m_[qs][r], tm[r]);
                al[r] = exp2f(m_[qs][r] - mn[r]);
                ps_[r] = 0.f;
            }
            m_[qs] = mn;
            // p = exp2(S - m) (log2 domain: theta pre-scaled by log2e); store bf16
#pragma unroll
            for (int ss = 0; ss < 4; ++ss)
#pragma unroll
                for (int r = 0; r < 4; ++r) {
                    const float p = exp2f(S[qs][ss][r] - mn[r]);
                    ps_[r] += p;
                    Pw[(qs * 16 + quad * 4 + r) * 72 + ss * 16 + lr] =
                        (unsigned short)(__float_as_uint(p) >> 16);
                }
#pragma unroll
            for (int r = 0; r < 4; ++r) l_[qs][r] = l_[qs][r] * al[r] + ps_[r];
#pragma unroll
            for (int cs = 0; cs < 2; ++cs)
#pragma unroll
                for (int r = 0; r < 4; ++r) O[qs][cs][r] *= al[r];
        }

        // PV: A = P[q=qs*16+lr][k=s] from LDS; B = G[n=c=cs*16+lr][k=s] from gT
#pragma unroll
        for (int kc = 0; kc < 2; ++kc) {
            s16x8 Gf[2];
#pragma unroll
            for (int cs = 0; cs < 2; ++cs)
                Gf[cs] = LD8G(gp + (size_t)(cs * 16 + lr) * NPS + s0 + kc * 32 + quad * 8);
#pragma unroll
            for (int qs = 0; qs < 2; ++qs) {
                const s16x8 Pf = *(const s16x8*)(Pw + (qs * 16 + lr) * 72 + kc * 32 + quad * 8);
#pragma unroll
                for (int cs = 0; cs < 2; ++cs)
                    O[qs][cs] = __builtin_amdgcn_mfma_f32_16x16x32_bf16(Pf, Gf[cs], O[qs][cs], 0, 0, 0);
            }
        }
    }

    // final l: butterfly-sum partials over the 16-lane s-groups
#pragma unroll
    for (int qs = 0; qs < 2; ++qs)
#pragma unroll
        for (int r = 0; r < 4; ++r) {
            float v = l_[qs][r];
            v += __shfl_xor(v, 1);
            v += __shfl_xor(v, 2);
            v += __shfl_xor(v, 4);
            v += __shfl_xor(v, 8);
            l_[qs][r] = v;
        }

    __syncthreads();                            // all waves done reading their Pw
    float* otile = (float*)smem;                // [32 c][132 q-stride]
#pragma unroll
    for (int qs = 0; qs < 2; ++qs)
#pragma unroll
        for (int cs = 0; cs < 2; ++cs)
#pragma unroll
            for (int r = 0; r < 4; ++r) {
                const int ql = wave * 32 + qs * 16 + quad * 4 + r;
                otile[(cs * 16 + lr) * 132 + ql] = O[qs][cs][r] / l_[qs][r];
            }
    __syncthreads();

    // Wo epilogue + residual
    const int qe = tid & 127;
    const int half = tid >> 7;
    float acc[32];
#pragma unroll
    for (int j = 0; j < 32; ++j) acc[j] = 0.f;
    for (int c = 0; c < 32; ++c) {
        const float ov = otile[c * 132 + qe];
#pragma unroll
        for (int j = 0; j < 32; ++j)
            acc[j] += Wo[(half * 32 + j) * 32 + c] * ov;   // wave-uniform -> s_load
    }
    const float gam = gamma_p[0];
#pragma unroll
    for (int j = 0; j < 32; ++j) {
        const size_t a = ((size_t)(b * NC + half * 32 + j)) * HWs + q0 + qe;
        out[a] = gam * acc[j] + x[a];
    }
}

extern "C" void kernel_launch(void* const* d_in, const int* in_sizes, int n_in,
                              void* d_out, int out_size, void* d_ws, size_t ws_size,
                              hipStream_t stream) {
    const float* x     = (const float*)d_in[0];
    const float* Wt    = (const float*)d_in[1];
    const float* Wp    = (const float*)d_in[2];
    const float* Wg    = (const float*)d_in[3];
    const float* Wo    = (const float*)d_in[4];
    const float* gamma = (const float*)d_in[5];
    float* out = (float*)d_out;
    unsigned short* ws = (unsigned short*)d_ws;

    k_proj<<<384, 256, 0, stream>>>(x, Wt, Wp, Wg, ws);
    k_attn<<<512, 256, 0, stream>>>(x, Wo, gamma, ws, out);
}